// Round 5
// baseline (312.689 us; speedup 1.0000x reference)
//
#include <hip/hip_runtime.h>
#include <math.h>

// ViT Vector Quantizer: z [32,1024,32] f32, embedding [8192,32] f32.
// Outputs (concat, read as f32): z_q_out [N*D], loss [1], idx [N] (as floats).
//
// R5: split-bf16 MFMA argmin + exact-rescore safety net.
//   K0 k_prep        : normalize codes -> en (f32), en_h; split en and znorm into
//                      bf16 hi/lo pre-swizzled into MFMA fragment order; cnt=loss=0.
//   K1 k_argmin_mfma : D=32 == K of mfma_f32_16x16x32_bf16. 3 MFMAs/tile
//                      (hi*hi + hi*lo + lo*hi) -> |err| <= ~2.4e-5 vs fp32.
//                      Track per-row (best, 2nd-best, kb). gap < MARGIN -> flag row.
//   K2 k_cleanup     : flagged rows (~200 expected) exact-rescanned over all 8192
//                      codes with the R4 fp32 formula (first-min tie-break).
//   K3 k_epi         : gather en[idx], write z_q_out, idx, loss.
// Non-flagged rows: approx gap > MARGIN > 2*err_bound => approx winner == exact
// winner. Flagged rows: computed exactly. Correctness == R4's (which passed).

#define D 32
#define KCODES 8192
#define MARGIN 2.5e-4f     // >= 10x worst-case split-bf16 error bound
#define EPS 1e-12f

typedef short bf16x8 __attribute__((ext_vector_type(8)));
typedef unsigned short u16x8 __attribute__((ext_vector_type(8)));
typedef float f32x4 __attribute__((ext_vector_type(4)));

static __device__ __forceinline__ unsigned short f2bf(float x) {  // RNE bf16 bits
  unsigned u = __float_as_uint(x);
  return (unsigned short)((u + 0x7FFFu + ((u >> 16) & 1u)) >> 16);
}
static __device__ __forceinline__ float bf2f(unsigned short s) {
  return __uint_as_float(((unsigned)s) << 16);
}

// MFMA fragment layouts (m89/m120-verified on gfx950):
//   A[m][k]: m = lane&15, k = (lane>>4)*8 + j   (8 bf16 per lane, contiguous 16B)
//   B[k][n]: n = lane&15, k = (lane>>4)*8 + j   (mirror of A)
//   C[m][n]: n = lane&15, m = (lane>>4)*4 + reg
// Swizzled storage: group of 16 vectors -> 512 shorts; lane l's 16B at l*8.

__global__ __launch_bounds__(256) void k_prep(const float* __restrict__ z,
                                              const float* __restrict__ emb,
                                              float* __restrict__ en,
                                              float* __restrict__ en_h,
                                              unsigned short* __restrict__ eswz,
                                              unsigned short* __restrict__ zswz_hi,
                                              unsigned short* __restrict__ zswz_lo,
                                              int* __restrict__ cnt,
                                              float* __restrict__ loss,
                                              int N) {
  int v = blockIdx.x * 256 + threadIdx.x;
  if (v == 0) { *cnt = 0; *loss = 0.f; }
  if (v >= KCODES + N) return;
  const float* src = (v < KCODES) ? (emb + (size_t)v * D) : (z + (size_t)(v - KCODES) * D);

  float x[D];
  const float4* p = reinterpret_cast<const float4*>(src);
#pragma unroll
  for (int j = 0; j < D / 4; ++j) {
    float4 q = p[j];
    x[4 * j + 0] = q.x; x[4 * j + 1] = q.y; x[4 * j + 2] = q.z; x[4 * j + 3] = q.w;
  }
  float ss = 0.f;
#pragma unroll
  for (int j = 0; j < D; ++j) ss = fmaf(x[j], x[j], ss);
  float n = fmaxf(sqrtf(ss), EPS);
#pragma unroll
  for (int j = 0; j < D; ++j) x[j] = x[j] / n;   // true division mirrors reference

  unsigned short hi[D], lo[D];
#pragma unroll
  for (int j = 0; j < D; ++j) {
    hi[j] = f2bf(x[j]);
    lo[j] = f2bf(x[j] - bf2f(hi[j]));   // x - bf16(x) is exact in fp32
  }

  if (v < KCODES) {
    // en (f32) + h for exact rescore & epilogue
    float4* o = reinterpret_cast<float4*>(en + (size_t)v * D);
    float s2 = 0.f;
#pragma unroll
    for (int j = 0; j < D / 4; ++j) {
      float4 q = {x[4 * j], x[4 * j + 1], x[4 * j + 2], x[4 * j + 3]};
      s2 = fmaf(q.x, q.x, fmaf(q.y, q.y, fmaf(q.z, q.z, fmaf(q.w, q.w, s2))));
      o[j] = q;
    }
    en_h[v] = 0.5f * s2;
    // B-fragment swizzle: tile tl=v>>4, col m=v&15; per quad q: dims 8q..8q+7
    // land at shorts [tl*1024 + (q*16+m)*8 + j]; lo at +512.
    int tl = v >> 4, m = v & 15;
#pragma unroll
    for (int q = 0; q < 4; ++q) {
      u16x8 hv, lv;
#pragma unroll
      for (int j = 0; j < 8; ++j) { hv[j] = hi[8 * q + j]; lv[j] = lo[8 * q + j]; }
      *(u16x8*)(eswz + (size_t)tl * 1024 + (q * 16 + m) * 8) = hv;
      *(u16x8*)(eswz + (size_t)tl * 1024 + 512 + (q * 16 + m) * 8) = lv;
    }
  } else {
    int r = v - KCODES;
    int g = r >> 4, m = r & 15;     // A-fragment swizzle, group g: 512 shorts
#pragma unroll
    for (int q = 0; q < 4; ++q) {
      u16x8 hv, lv;
#pragma unroll
      for (int j = 0; j < 8; ++j) { hv[j] = hi[8 * q + j]; lv[j] = lo[8 * q + j]; }
      *(u16x8*)(zswz_hi + (size_t)g * 512 + (q * 16 + m) * 8) = hv;
      *(u16x8*)(zswz_lo + (size_t)g * 512 + (q * 16 + m) * 8) = lv;
    }
  }
}

__global__ __launch_bounds__(256) void k_argmin_mfma(
    const unsigned short* __restrict__ zswz_hi,
    const unsigned short* __restrict__ zswz_lo,
    const unsigned short* __restrict__ eswz,
    int* __restrict__ idx_ws, int* __restrict__ list, int* __restrict__ cnt) {
  __shared__ unsigned short lds_sh[16384];   // 32 KB: 16 tiles x (hi 1KB | lo 1KB)

  const int tid = threadIdx.x;
  const int wid = tid >> 6, lane = tid & 63;
  const int lane15 = lane & 15, quad = lane >> 4;
  const int g = blockIdx.x * 4 + wid;        // 16-row group per wave

  const bf16x8 zhi = *(const bf16x8*)(zswz_hi + (size_t)g * 512 + lane * 8);
  const bf16x8 zlo = *(const bf16x8*)(zswz_lo + (size_t)g * 512 + lane * 8);

  float s1[4], s2[4];
  int kb[4];
#pragma unroll
  for (int r = 0; r < 4; ++r) { s1[r] = -3.4e38f; s2[r] = -3.4e38f; kb[r] = 0; }
  const f32x4 zero4 = {0.f, 0.f, 0.f, 0.f};

  // register-double-buffered chunk staging: 32 KB/chunk, 128 B/thread
  const float4* gsrc = reinterpret_cast<const float4*>(eswz);
  float4 pre[8];
#pragma unroll
  for (int i = 0; i < 8; ++i) pre[i] = gsrc[i * 256 + tid];

  for (int c = 0; c < 32; ++c) {
    float4* lf = reinterpret_cast<float4*>(lds_sh);
#pragma unroll
    for (int i = 0; i < 8; ++i) lf[i * 256 + tid] = pre[i];
    const float4* gn = gsrc + (size_t)((c + 1 < 32) ? c + 1 : 31) * 2048;
#pragma unroll
    for (int i = 0; i < 8; ++i) pre[i] = gn[i * 256 + tid];   // prefetch next
    __syncthreads();

    int kcur = c * 256 + lane15;
#pragma unroll
    for (int t = 0; t < 16; ++t) {
      bf16x8 bhi = *(const bf16x8*)(lds_sh + t * 1024 + lane * 8);
      bf16x8 blo = *(const bf16x8*)(lds_sh + t * 1024 + 512 + lane * 8);
      f32x4 acc = __builtin_amdgcn_mfma_f32_16x16x32_bf16(zhi, bhi, zero4, 0, 0, 0);
      acc = __builtin_amdgcn_mfma_f32_16x16x32_bf16(zhi, blo, acc, 0, 0, 0);
      acc = __builtin_amdgcn_mfma_f32_16x16x32_bf16(zlo, bhi, acc, 0, 0, 0);
#pragma unroll
      for (int r = 0; r < 4; ++r) {
        float cv = acc[r];
        bool cond = cv > s1[r];                 // strict: keep earliest on ties
        kb[r] = cond ? kcur : kb[r];
        s2[r] = fmaxf(s2[r], fminf(cv, s1[r])); // running 2nd-best
        s1[r] = fmaxf(s1[r], cv);
      }
      kcur += 16;
    }
    __syncthreads();
  }

  // merge across the 16 lanes sharing this quad's 4 rows
  unsigned long long packed[4];
#pragma unroll
  for (int r = 0; r < 4; ++r) {
    unsigned o = __float_as_uint(s1[r]);
    o = (o & 0x80000000u) ? ~o : (o | 0x80000000u);        // monotone in s1
    packed[r] = ((unsigned long long)o << 32) | (unsigned)(8191 - kb[r]);
  }
#pragma unroll
  for (int m = 1; m <= 8; m <<= 1) {
#pragma unroll
    for (int r = 0; r < 4; ++r) {
      unsigned long long op = __shfl_xor(packed[r], m, 64);
      float os1 = __shfl_xor(s1[r], m, 64);
      float os2 = __shfl_xor(s2[r], m, 64);
      s2[r] = fmaxf(fmaxf(s2[r], os2), fminf(s1[r], os1)); // union 2nd-best
      s1[r] = fmaxf(s1[r], os1);
      packed[r] = (op > packed[r]) ? op : packed[r];        // max s1, tie->min k
    }
  }
  if (lane15 == 0) {
#pragma unroll
    for (int r = 0; r < 4; ++r) {
      int row = g * 16 + quad * 4 + r;
      idx_ws[row] = 8191 - (int)(unsigned)(packed[r] & 0xFFFFFFFFull);
      if (s1[r] - s2[r] < MARGIN) {            // ambiguous -> exact rescore
        int pos = atomicAdd(cnt, 1);
        list[pos] = row;
      }
    }
  }
}

// Exact fp32 rescan (R4 formula, first-min tie-break) for flagged rows.
__global__ __launch_bounds__(64) void k_cleanup(const float* __restrict__ z,
                                                const float* __restrict__ en,
                                                const float* __restrict__ en_h,
                                                int* __restrict__ idx_ws,
                                                const int* __restrict__ list,
                                                const int* __restrict__ cnt) {
  const int lane = threadIdx.x;
  const int total = *cnt;
  for (int i = blockIdx.x; i < total; i += gridDim.x) {
    int row = list[i];
    const float* zr = z + (size_t)row * D;     // wave-uniform -> scalar loads
    float v[D];
    float ss = 0.f;
#pragma unroll
    for (int j = 0; j < D; ++j) v[j] = zr[j];
#pragma unroll
    for (int j = 0; j < D; ++j) ss = fmaf(v[j], v[j], ss);
    float n = fmaxf(sqrtf(ss), EPS);
#pragma unroll
    for (int j = 0; j < D; ++j) v[j] = v[j] / n;

    unsigned long long best = 0ull;
    for (int k = lane; k < KCODES; k += 64) {
      const float* er = en + (size_t)k * D;
      float a = -en_h[k];
#pragma unroll
      for (int j = 0; j < D; ++j) a = fmaf(v[j], er[j], a);  // R4-exact order
      unsigned o = __float_as_uint(a);
      o = (o & 0x80000000u) ? ~o : (o | 0x80000000u);
      unsigned long long pk = ((unsigned long long)o << 32) | (unsigned)(8191 - k);
      best = (pk > best) ? pk : best;          // max s, tie -> min k
    }
#pragma unroll
    for (int m = 32; m >= 1; m >>= 1) {
      unsigned long long o = __shfl_xor(best, m, 64);
      best = (o > best) ? o : best;
    }
    if (lane == 0) idx_ws[row] = 8191 - (int)(unsigned)(best & 0xFFFFFFFFull);
  }
}

__global__ __launch_bounds__(256) void k_epi(const float* __restrict__ z,
                                             const float* __restrict__ en,
                                             const int* __restrict__ idx_ws,
                                             float* __restrict__ out_z,
                                             float* __restrict__ loss,
                                             float* __restrict__ out_idx,
                                             float scale) {
  int row = blockIdx.x * 256 + threadIdx.x;
  int kb = idx_ws[row];
  out_idx[row] = (float)kb;  // whole out buffer read back as f32

  const float4* p = reinterpret_cast<const float4*>(z + (size_t)row * D);
  float4 q[D / 4];
#pragma unroll
  for (int j = 0; j < D / 4; ++j) q[j] = p[j];
  float ss = 0.f;
#pragma unroll
  for (int j = 0; j < D / 4; ++j)
    ss = fmaf(q[j].x, q[j].x, fmaf(q[j].y, q[j].y, fmaf(q[j].z, q[j].z, fmaf(q[j].w, q[j].w, ss))));
  float n = fmaxf(sqrtf(ss), EPS);

  const float4* ep = reinterpret_cast<const float4*>(en + (size_t)kb * D);
  float4* op = reinterpret_cast<float4*>(out_z + (size_t)row * D);
  float s = 0.f;
#pragma unroll
  for (int j = 0; j < D / 4; ++j) {
    float4 e = ep[j];
    float4 o;
    o.x = q[j].x + (e.x - q[j].x);  // STE forward value, reference op order
    o.y = q[j].y + (e.y - q[j].y);
    o.z = q[j].z + (e.z - q[j].z);
    o.w = q[j].w + (e.w - q[j].w);
    op[j] = o;
    float dx = e.x - q[j].x / n;  float dy = e.y - q[j].y / n;
    float dz = e.z - q[j].z / n;  float dw = e.w - q[j].w / n;
    s = fmaf(dx, dx, fmaf(dy, dy, fmaf(dz, dz, fmaf(dw, dw, s))));
  }

#pragma unroll
  for (int off = 32; off > 0; off >>= 1) s += __shfl_down(s, off, 64);
  __shared__ float wsum[4];
  int lane = threadIdx.x & 63, wid = threadIdx.x >> 6;
  if (lane == 0) wsum[wid] = s;
  __syncthreads();
  if (threadIdx.x == 0) {
    float tt = (wsum[0] + wsum[1]) + (wsum[2] + wsum[3]);
    atomicAdd(loss, tt * scale);
  }
}

extern "C" void kernel_launch(void* const* d_in, const int* in_sizes, int n_in,
                              void* d_out, int out_size, void* d_ws, size_t ws_size,
                              hipStream_t stream) {
  const float* z = (const float*)d_in[0];
  const float* emb = (const float*)d_in[1];
  const int N = in_sizes[0] / D;  // 32768
  const int K = in_sizes[1] / D;  // 8192

  float* out = (float*)d_out;
  float* out_z = out;                        // N*D
  float* loss = out + (size_t)N * D;         // 1
  float* out_idx = out + (size_t)N * D + 1;  // N

  // ws layout (~6.4 MB; R3/R4 WRITE_SIZE=8MB proves ws >= 9.4 MB)
  char* w = (char*)d_ws;
  float* en = (float*)w;                         w += (size_t)K * D * 4;   // 1 MB
  float* en_h = (float*)w;                       w += (size_t)K * 4;       // 32 KB
  unsigned short* eswz = (unsigned short*)w;     w += (size_t)K * D * 2 * 2; // 1 MB (hi+lo)
  unsigned short* zswz_hi = (unsigned short*)w;  w += (size_t)N * D * 2;   // 2 MB
  unsigned short* zswz_lo = (unsigned short*)w;  w += (size_t)N * D * 2;   // 2 MB
  int* idx_ws = (int*)w;                         w += (size_t)N * 4;       // 128 KB
  int* list = (int*)w;                           w += (size_t)N * 4;       // 128 KB
  int* cnt = (int*)w;

  k_prep<<<dim3((K + N) / 256), 256, 0, stream>>>(
      z, emb, en, en_h, eswz, zswz_hi, zswz_lo, cnt, loss, N);

  k_argmin_mfma<<<dim3(N / 64), 256, 0, stream>>>(
      zswz_hi, zswz_lo, eswz, idx_ws, list, cnt);

  k_cleanup<<<dim3(256), 64, 0, stream>>>(z, en, en_h, idx_ws, list, cnt);

  k_epi<<<dim3(N / 256), 256, 0, stream>>>(
      z, en, idx_ws, out_z, loss, out_idx, 1.25f / (float)((size_t)N * D));
}

// Round 6
// 264.705 us; speedup vs baseline: 1.1813x; 1.1813x over previous
//
#include <hip/hip_runtime.h>
#include <math.h>

// ViT Vector Quantizer: z [32,1024,32] f32, embedding [8192,32] f32.
// Outputs (concat, read as f32): z_q_out [N*D], loss [1], idx [N] (as floats).
//
// R6: split-bf16 MFMA argmin + exact-rescore safety net; async LDS staging.
//   K0 k_prep        : normalize codes -> en (f32), en_h; split en and znorm into
//                      bf16 hi/lo pre-swizzled into MFMA fragment order; cnt=loss=0.
//   K1 k_argmin_mfma : 3 MFMAs/tile (hi*hi + hi*lo + lo*hi), |err| <= ~1.2e-5.
//                      Codebook chunks staged global->LDS via
//                      __builtin_amdgcn_global_load_lds (NO VGPR round-trip --
//                      R5's register prefetch spilled to scratch: 226 MB writes).
//                      Double-buffered 2x32KB, 1 barrier/chunk. Track per-row
//                      (best, 2nd-best, kb); gap < MARGIN -> flag row.
//   K2 k_cleanup     : flagged rows exact-rescanned (R4 fp32 formula), wave/row.
//   K3 k_epi         : gather en[idx], write z_q_out, idx, loss.

#define D 32
#define KCODES 8192
#define MARGIN 2.5e-4f     // ~20x worst-case split-bf16 error bound
#define EPS 1e-12f

typedef short bf16x8 __attribute__((ext_vector_type(8)));
typedef unsigned short u16x8 __attribute__((ext_vector_type(8)));
typedef float f32x4 __attribute__((ext_vector_type(4)));

static __device__ __forceinline__ unsigned short f2bf(float x) {  // RNE bf16 bits
  unsigned u = __float_as_uint(x);
  return (unsigned short)((u + 0x7FFFu + ((u >> 16) & 1u)) >> 16);
}
static __device__ __forceinline__ float bf2f(unsigned short s) {
  return __uint_as_float(((unsigned)s) << 16);
}
static __device__ __forceinline__ void gload_lds16(const void* g, void* l) {
  __builtin_amdgcn_global_load_lds(
      (const __attribute__((address_space(1))) void*)g,
      (__attribute__((address_space(3))) void*)l, 16, 0, 0);
}

// MFMA fragment layouts (m89/m120-verified on gfx950):
//   A[m][k]: m = lane&15, k = (lane>>4)*8 + j   (8 bf16/lane, contiguous 16B)
//   B[k][n]: n = lane&15, k = (lane>>4)*8 + j   (mirror of A)
//   C[m][n]: n = lane&15, m = (lane>>4)*4 + reg

__global__ __launch_bounds__(256) void k_prep(const float* __restrict__ z,
                                              const float* __restrict__ emb,
                                              float* __restrict__ en,
                                              float* __restrict__ en_h,
                                              unsigned short* __restrict__ eswz,
                                              unsigned short* __restrict__ zswz_hi,
                                              unsigned short* __restrict__ zswz_lo,
                                              int* __restrict__ cnt,
                                              float* __restrict__ loss,
                                              int N) {
  int v = blockIdx.x * 256 + threadIdx.x;
  if (v == 0) { *cnt = 0; *loss = 0.f; }
  if (v >= KCODES + N) return;
  const float* src = (v < KCODES) ? (emb + (size_t)v * D) : (z + (size_t)(v - KCODES) * D);

  float x[D];
  const float4* p = reinterpret_cast<const float4*>(src);
#pragma unroll
  for (int j = 0; j < D / 4; ++j) {
    float4 q = p[j];
    x[4 * j + 0] = q.x; x[4 * j + 1] = q.y; x[4 * j + 2] = q.z; x[4 * j + 3] = q.w;
  }
  float ss = 0.f;
#pragma unroll
  for (int j = 0; j < D; ++j) ss = fmaf(x[j], x[j], ss);
  float n = fmaxf(sqrtf(ss), EPS);
#pragma unroll
  for (int j = 0; j < D; ++j) x[j] = x[j] / n;   // true division mirrors reference

  unsigned short hi[D], lo[D];
#pragma unroll
  for (int j = 0; j < D; ++j) {
    hi[j] = f2bf(x[j]);
    lo[j] = f2bf(x[j] - bf2f(hi[j]));   // x - bf16(x) exact in fp32
  }

  if (v < KCODES) {
    float4* o = reinterpret_cast<float4*>(en + (size_t)v * D);
    float s2 = 0.f;
#pragma unroll
    for (int j = 0; j < D / 4; ++j) {
      float4 q = {x[4 * j], x[4 * j + 1], x[4 * j + 2], x[4 * j + 3]};
      s2 = fmaf(q.x, q.x, fmaf(q.y, q.y, fmaf(q.z, q.z, fmaf(q.w, q.w, s2))));
      o[j] = q;
    }
    en_h[v] = 0.5f * s2;
    // B-fragment swizzle: tile tl=v>>4, col m=v&15; quad q covers dims 8q..8q+7
    int tl = v >> 4, m = v & 15;
#pragma unroll
    for (int q = 0; q < 4; ++q) {
      u16x8 hv, lv;
#pragma unroll
      for (int j = 0; j < 8; ++j) { hv[j] = hi[8 * q + j]; lv[j] = lo[8 * q + j]; }
      *(u16x8*)(eswz + (size_t)tl * 1024 + (q * 16 + m) * 8) = hv;
      *(u16x8*)(eswz + (size_t)tl * 1024 + 512 + (q * 16 + m) * 8) = lv;
    }
  } else {
    int r = v - KCODES;
    int g = r >> 4, m = r & 15;     // A-fragment swizzle
#pragma unroll
    for (int q = 0; q < 4; ++q) {
      u16x8 hv, lv;
#pragma unroll
      for (int j = 0; j < 8; ++j) { hv[j] = hi[8 * q + j]; lv[j] = lo[8 * q + j]; }
      *(u16x8*)(zswz_hi + (size_t)g * 512 + (q * 16 + m) * 8) = hv;
      *(u16x8*)(zswz_lo + (size_t)g * 512 + (q * 16 + m) * 8) = lv;
    }
  }
}

// 512 threads = 8 waves, each wave owns one 16-row group; 256 blocks = 1/CU.
__global__ __launch_bounds__(512, 1) void k_argmin_mfma(
    const unsigned short* __restrict__ zswz_hi,
    const unsigned short* __restrict__ zswz_lo,
    const unsigned short* __restrict__ eswz,
    int* __restrict__ idx_ws, int* __restrict__ list, int* __restrict__ cnt) {
  __shared__ unsigned short lds_sh[2][16384];   // 2 x 32 KB double buffer

  const int tid = threadIdx.x;
  const int wid = tid >> 6, lane = tid & 63;
  const int lane15 = lane & 15, quad = lane >> 4;
  const int g = blockIdx.x * 8 + wid;           // 16-row group per wave

  const bf16x8 zhi = *(const bf16x8*)(zswz_hi + (size_t)g * 512 + lane * 8);
  const bf16x8 zlo = *(const bf16x8*)(zswz_lo + (size_t)g * 512 + lane * 8);

  float s1[4], s2[4];
  int kb[4];
#pragma unroll
  for (int r = 0; r < 4; ++r) { s1[r] = -3.4e38f; s2[r] = -3.4e38f; kb[r] = 0; }
  const f32x4 zero4 = {0.f, 0.f, 0.f, 0.f};

  // async stage: chunk c = 32 KB = 2048 float4; 4 x 16B per thread (512 thr)
  const float4* gall = reinterpret_cast<const float4*>(eswz);
#pragma unroll
  for (int i = 0; i < 4; ++i) {   // stage chunk 0 into buf 0
    int off = i * 512 + tid;      // lane-contiguous within each wave
    gload_lds16(gall + off, (char*)&lds_sh[0][0] + (size_t)off * 16);
  }

  for (int c = 0; c < 32; ++c) {
    __syncthreads();              // drains vmcnt -> buffer c&1 fully staged
    if (c + 1 < 32) {             // overlap next DMA with this chunk's compute
      const float4* gn = gall + (size_t)(c + 1) * 2048;
      char* dst = (char*)&lds_sh[(c + 1) & 1][0];
#pragma unroll
      for (int i = 0; i < 4; ++i) {
        int off = i * 512 + tid;
        gload_lds16(gn + off, dst + (size_t)off * 16);
      }
    }
    const unsigned short* buf = &lds_sh[c & 1][0];
    int kcur = c * 256 + lane15;
#pragma unroll
    for (int t = 0; t < 16; ++t) {
      bf16x8 bhi = *(const bf16x8*)(buf + t * 1024 + lane * 8);
      bf16x8 blo = *(const bf16x8*)(buf + t * 1024 + 512 + lane * 8);
      f32x4 acc = __builtin_amdgcn_mfma_f32_16x16x32_bf16(zhi, bhi, zero4, 0, 0, 0);
      acc = __builtin_amdgcn_mfma_f32_16x16x32_bf16(zhi, blo, acc, 0, 0, 0);
      acc = __builtin_amdgcn_mfma_f32_16x16x32_bf16(zlo, bhi, acc, 0, 0, 0);
#pragma unroll
      for (int r = 0; r < 4; ++r) {
        float cv = acc[r];
        bool cond = cv > s1[r];                 // strict: keep earliest on ties
        kb[r] = cond ? kcur : kb[r];
        s2[r] = fmaxf(s2[r], fminf(cv, s1[r])); // running 2nd-best
        s1[r] = fmaxf(s1[r], cv);
      }
      kcur += 16;
    }
  }

  // merge across the 16 lanes sharing this quad's 4 rows
  unsigned long long packed[4];
#pragma unroll
  for (int r = 0; r < 4; ++r) {
    unsigned o = __float_as_uint(s1[r]);
    o = (o & 0x80000000u) ? ~o : (o | 0x80000000u);        // monotone in s1
    packed[r] = ((unsigned long long)o << 32) | (unsigned)(8191 - kb[r]);
  }
#pragma unroll
  for (int m = 1; m <= 8; m <<= 1) {
#pragma unroll
    for (int r = 0; r < 4; ++r) {
      unsigned long long op = __shfl_xor(packed[r], m, 64);
      float os1 = __shfl_xor(s1[r], m, 64);
      float os2 = __shfl_xor(s2[r], m, 64);
      s2[r] = fmaxf(fmaxf(s2[r], os2), fminf(s1[r], os1)); // union 2nd-best
      s1[r] = fmaxf(s1[r], os1);
      packed[r] = (op > packed[r]) ? op : packed[r];        // max s1, tie->min k
    }
  }
  if (lane15 == 0) {
#pragma unroll
    for (int r = 0; r < 4; ++r) {
      int row = g * 16 + quad * 4 + r;
      idx_ws[row] = 8191 - (int)(unsigned)(packed[r] & 0xFFFFFFFFull);
      if (s1[r] - s2[r] < MARGIN) {            // ambiguous -> exact rescore
        int pos = atomicAdd(cnt, 1);
        list[pos] = row;
      }
    }
  }
}

// Exact fp32 rescan (R4 formula, first-min tie-break), one wave per flagged row.
__global__ __launch_bounds__(256) void k_cleanup(const float* __restrict__ z,
                                                 const float* __restrict__ en,
                                                 const float* __restrict__ en_h,
                                                 int* __restrict__ idx_ws,
                                                 const int* __restrict__ list,
                                                 const int* __restrict__ cnt) {
  const int lane = threadIdx.x & 63;
  const int gw = blockIdx.x * 4 + (threadIdx.x >> 6);   // global wave id
  const int total = *cnt;
  for (int i = gw; i < total; i += gridDim.x * 4) {
    int row = list[i];
    const float* zr = z + (size_t)row * D;     // wave-uniform -> scalar loads
    float v[D];
    float ss = 0.f;
#pragma unroll
    for (int j = 0; j < D; ++j) v[j] = zr[j];
#pragma unroll
    for (int j = 0; j < D; ++j) ss = fmaf(v[j], v[j], ss);
    float n = fmaxf(sqrtf(ss), EPS);
#pragma unroll
    for (int j = 0; j < D; ++j) v[j] = v[j] / n;

    unsigned long long best = 0ull;
    for (int k = lane; k < KCODES; k += 64) {
      const float* er = en + (size_t)k * D;
      float a = -en_h[k];
#pragma unroll
      for (int j = 0; j < D; ++j) a = fmaf(v[j], er[j], a);  // R4-exact order
      unsigned o = __float_as_uint(a);
      o = (o & 0x80000000u) ? ~o : (o | 0x80000000u);
      unsigned long long pk = ((unsigned long long)o << 32) | (unsigned)(8191 - k);
      best = (pk > best) ? pk : best;          // max s, tie -> min k
    }
#pragma unroll
    for (int m = 32; m >= 1; m >>= 1) {
      unsigned long long o = __shfl_xor(best, m, 64);
      best = (o > best) ? o : best;
    }
    if (lane == 0) idx_ws[row] = 8191 - (int)(unsigned)(best & 0xFFFFFFFFull);
  }
}

__global__ __launch_bounds__(256) void k_epi(const float* __restrict__ z,
                                             const float* __restrict__ en,
                                             const int* __restrict__ idx_ws,
                                             float* __restrict__ out_z,
                                             float* __restrict__ loss,
                                             float* __restrict__ out_idx,
                                             float scale) {
  int row = blockIdx.x * 256 + threadIdx.x;
  int kb = idx_ws[row];
  out_idx[row] = (float)kb;  // whole out buffer read back as f32

  const float4* p = reinterpret_cast<const float4*>(z + (size_t)row * D);
  float4 q[D / 4];
#pragma unroll
  for (int j = 0; j < D / 4; ++j) q[j] = p[j];
  float ss = 0.f;
#pragma unroll
  for (int j = 0; j < D / 4; ++j)
    ss = fmaf(q[j].x, q[j].x, fmaf(q[j].y, q[j].y, fmaf(q[j].z, q[j].z, fmaf(q[j].w, q[j].w, ss))));
  float n = fmaxf(sqrtf(ss), EPS);

  const float4* ep = reinterpret_cast<const float4*>(en + (size_t)kb * D);
  float4* op = reinterpret_cast<float4*>(out_z + (size_t)row * D);
  float s = 0.f;
#pragma unroll
  for (int j = 0; j < D / 4; ++j) {
    float4 e = ep[j];
    float4 o;
    o.x = q[j].x + (e.x - q[j].x);  // STE forward value, reference op order
    o.y = q[j].y + (e.y - q[j].y);
    o.z = q[j].z + (e.z - q[j].z);
    o.w = q[j].w + (e.w - q[j].w);
    op[j] = o;
    float dx = e.x - q[j].x / n;  float dy = e.y - q[j].y / n;
    float dz = e.z - q[j].z / n;  float dw = e.w - q[j].w / n;
    s = fmaf(dx, dx, fmaf(dy, dy, fmaf(dz, dz, fmaf(dw, dw, s))));
  }

#pragma unroll
  for (int off = 32; off > 0; off >>= 1) s += __shfl_down(s, off, 64);
  __shared__ float wsum[4];
  int lane = threadIdx.x & 63, wid = threadIdx.x >> 6;
  if (lane == 0) wsum[wid] = s;
  __syncthreads();
  if (threadIdx.x == 0) {
    float tt = (wsum[0] + wsum[1]) + (wsum[2] + wsum[3]);
    atomicAdd(loss, tt * scale);
  }
}

extern "C" void kernel_launch(void* const* d_in, const int* in_sizes, int n_in,
                              void* d_out, int out_size, void* d_ws, size_t ws_size,
                              hipStream_t stream) {
  const float* z = (const float*)d_in[0];
  const float* emb = (const float*)d_in[1];
  const int N = in_sizes[0] / D;  // 32768
  const int K = in_sizes[1] / D;  // 8192

  float* out = (float*)d_out;
  float* out_z = out;                        // N*D
  float* loss = out + (size_t)N * D;         // 1
  float* out_idx = out + (size_t)N * D + 1;  // N

  // ws layout (~6.4 MB; R3/R4 WRITE_SIZE=8MB proves ws >= 9.4 MB)
  char* w = (char*)d_ws;
  float* en = (float*)w;                         w += (size_t)K * D * 4;     // 1 MB
  float* en_h = (float*)w;                       w += (size_t)K * 4;         // 32 KB
  unsigned short* eswz = (unsigned short*)w;     w += (size_t)K * D * 2 * 2; // 1 MB (hi+lo)
  unsigned short* zswz_hi = (unsigned short*)w;  w += (size_t)N * D * 2;     // 2 MB
  unsigned short* zswz_lo = (unsigned short*)w;  w += (size_t)N * D * 2;     // 2 MB
  int* idx_ws = (int*)w;                         w += (size_t)N * 4;         // 128 KB
  int* list = (int*)w;                           w += (size_t)N * 4;         // 128 KB
  int* cnt = (int*)w;

  k_prep<<<dim3((K + N) / 256), 256, 0, stream>>>(
      z, emb, en, en_h, eswz, zswz_hi, zswz_lo, cnt, loss, N);

  k_argmin_mfma<<<dim3(N / 128), 512, 0, stream>>>(
      zswz_hi, zswz_lo, eswz, idx_ws, list, cnt);

  k_cleanup<<<dim3(512), 256, 0, stream>>>(z, en, en_h, idx_ws, list, cnt);

  k_epi<<<dim3(N / 256), 256, 0, stream>>>(
      z, en, idx_ws, out_z, loss, out_idx, 1.25f / (float)((size_t)N * D));
}

// Round 7
// 188.328 us; speedup vs baseline: 1.6603x; 1.4056x over previous
//
#include <hip/hip_runtime.h>
#include <math.h>

// ViT Vector Quantizer: z [32,1024,32] f32, embedding [8192,32] f32.
// Outputs (concat, read as f32): z_q_out [N*D], loss [1], idx [N] (as floats).
//
// R7: split-bf16 MFMA argmin + parallel exact-rescore.
//   K0 k_prep        : normalize codes -> en, en_h; bf16 hi/lo swizzled into MFMA
//                      fragment order; init cnt/loss/mp2.
//   K1 k_argmin_mfma : 3 MFMAs/tile (hi*hi+hi*lo+lo*hi); double-buffered 32 KB
//                      chunks via global_load_lds; 256-thr blocks, grid 512 =
//                      2 blocks/CU so barriers overlap across blocks (m114).
//                      gap < MARGIN -> sentinel idx_ws[row] = -(pos+1), list[pos]=row.
//   K2 k_cleanup     : THREAD-PER-CODE exact fp32 rescore (R6's wave-per-row scan
//                      was a 116 us serial latency chain); block-reduce + u64
//                      atomicMax into mp2[pos].
//   K3 k_epi         : decode sentinel via mp2, gather en[idx], write outputs.

#define D 32
#define KCODES 8192
#define MARGIN 2.5e-4f     // ~20x worst-case split-bf16 error bound
#define EPS 1e-12f

typedef short bf16x8 __attribute__((ext_vector_type(8)));
typedef unsigned short u16x8 __attribute__((ext_vector_type(8)));
typedef float f32x4 __attribute__((ext_vector_type(4)));

static __device__ __forceinline__ unsigned short f2bf(float x) {  // RNE bf16 bits
  unsigned u = __float_as_uint(x);
  return (unsigned short)((u + 0x7FFFu + ((u >> 16) & 1u)) >> 16);
}
static __device__ __forceinline__ float bf2f(unsigned short s) {
  return __uint_as_float(((unsigned)s) << 16);
}
static __device__ __forceinline__ void gload_lds16(const void* g, void* l) {
  __builtin_amdgcn_global_load_lds(
      (const __attribute__((address_space(1))) void*)g,
      (__attribute__((address_space(3))) void*)l, 16, 0, 0);
}

// MFMA fragment layouts (empirically validated by R5/R6 exact-idx passes):
//   A[m][k]: m = lane&15, k = (lane>>4)*8 + j   (8 bf16/lane, contiguous 16B)
//   B[k][n]: n = lane&15, k = (lane>>4)*8 + j
//   C[m][n]: n = lane&15, m = (lane>>4)*4 + reg

__global__ __launch_bounds__(256) void k_prep(const float* __restrict__ z,
                                              const float* __restrict__ emb,
                                              float* __restrict__ en,
                                              float* __restrict__ en_h,
                                              unsigned short* __restrict__ eswz,
                                              unsigned short* __restrict__ zswz_hi,
                                              unsigned short* __restrict__ zswz_lo,
                                              int* __restrict__ cnt,
                                              float* __restrict__ loss,
                                              unsigned long long* __restrict__ mp2,
                                              int N) {
  int v = blockIdx.x * 256 + threadIdx.x;
  if (v == 0) { *cnt = 0; *loss = 0.f; }
  if (v >= KCODES + N) return;
  if (v >= KCODES) mp2[v - KCODES] = 0ull;   // atomicMax identity
  const float* src = (v < KCODES) ? (emb + (size_t)v * D) : (z + (size_t)(v - KCODES) * D);

  float x[D];
  const float4* p = reinterpret_cast<const float4*>(src);
#pragma unroll
  for (int j = 0; j < D / 4; ++j) {
    float4 q = p[j];
    x[4 * j + 0] = q.x; x[4 * j + 1] = q.y; x[4 * j + 2] = q.z; x[4 * j + 3] = q.w;
  }
  float ss = 0.f;
#pragma unroll
  for (int j = 0; j < D; ++j) ss = fmaf(x[j], x[j], ss);
  float n = fmaxf(sqrtf(ss), EPS);
#pragma unroll
  for (int j = 0; j < D; ++j) x[j] = x[j] / n;   // true division mirrors reference

  unsigned short hi[D], lo[D];
#pragma unroll
  for (int j = 0; j < D; ++j) {
    hi[j] = f2bf(x[j]);
    lo[j] = f2bf(x[j] - bf2f(hi[j]));   // x - bf16(x) exact in fp32
  }

  if (v < KCODES) {
    float4* o = reinterpret_cast<float4*>(en + (size_t)v * D);
    float s2 = 0.f;
#pragma unroll
    for (int j = 0; j < D / 4; ++j) {
      float4 q = {x[4 * j], x[4 * j + 1], x[4 * j + 2], x[4 * j + 3]};
      s2 = fmaf(q.x, q.x, fmaf(q.y, q.y, fmaf(q.z, q.z, fmaf(q.w, q.w, s2))));
      o[j] = q;
    }
    en_h[v] = 0.5f * s2;
    int tl = v >> 4, m = v & 15;    // B-fragment swizzle
#pragma unroll
    for (int q = 0; q < 4; ++q) {
      u16x8 hv, lv;
#pragma unroll
      for (int j = 0; j < 8; ++j) { hv[j] = hi[8 * q + j]; lv[j] = lo[8 * q + j]; }
      *(u16x8*)(eswz + (size_t)tl * 1024 + (q * 16 + m) * 8) = hv;
      *(u16x8*)(eswz + (size_t)tl * 1024 + 512 + (q * 16 + m) * 8) = lv;
    }
  } else {
    int r = v - KCODES;
    int g = r >> 4, m = r & 15;     // A-fragment swizzle
#pragma unroll
    for (int q = 0; q < 4; ++q) {
      u16x8 hv, lv;
#pragma unroll
      for (int j = 0; j < 8; ++j) { hv[j] = hi[8 * q + j]; lv[j] = lo[8 * q + j]; }
      *(u16x8*)(zswz_hi + (size_t)g * 512 + (q * 16 + m) * 8) = hv;
      *(u16x8*)(zswz_lo + (size_t)g * 512 + (q * 16 + m) * 8) = lv;
    }
  }
}

// 256 threads = 4 waves (one 16-row group each); grid 512 = 2 blocks/CU so one
// block's compute overlaps the other's barrier/DMA drain.
__global__ __launch_bounds__(256, 2) void k_argmin_mfma(
    const unsigned short* __restrict__ zswz_hi,
    const unsigned short* __restrict__ zswz_lo,
    const unsigned short* __restrict__ eswz,
    int* __restrict__ idx_ws, int* __restrict__ list, int* __restrict__ cnt) {
  __shared__ unsigned short lds_sh[2][16384];   // 2 x 32 KB double buffer

  const int tid = threadIdx.x;
  const int wid = tid >> 6, lane = tid & 63;
  const int lane15 = lane & 15, quad = lane >> 4;
  const int g = blockIdx.x * 4 + wid;           // 16-row group per wave

  const bf16x8 zhi = *(const bf16x8*)(zswz_hi + (size_t)g * 512 + lane * 8);
  const bf16x8 zlo = *(const bf16x8*)(zswz_lo + (size_t)g * 512 + lane * 8);

  float s1[4], s2[4];
  int kb[4];
#pragma unroll
  for (int r = 0; r < 4; ++r) { s1[r] = -3.4e38f; s2[r] = -3.4e38f; kb[r] = 0; }
  const f32x4 zero4 = {0.f, 0.f, 0.f, 0.f};

  // async stage: chunk = 32 KB = 2048 float4; 8 x 16B per thread (256 thr)
  const float4* gall = reinterpret_cast<const float4*>(eswz);
#pragma unroll
  for (int i = 0; i < 8; ++i) {   // stage chunk 0 into buf 0
    int off = i * 256 + tid;      // wave-uniform base + lane-contiguous (m104)
    gload_lds16(gall + off, (char*)&lds_sh[0][0] + (size_t)off * 16);
  }

  for (int c = 0; c < 32; ++c) {
    __syncthreads();              // drains vmcnt -> buffer c&1 fully staged
    if (c + 1 < 32) {             // next DMA overlaps this chunk's compute
      const float4* gn = gall + (size_t)(c + 1) * 2048;
      char* dst = (char*)&lds_sh[(c + 1) & 1][0];
#pragma unroll
      for (int i = 0; i < 8; ++i) {
        int off = i * 256 + tid;
        gload_lds16(gn + off, dst + (size_t)off * 16);
      }
    }
    const unsigned short* buf = &lds_sh[c & 1][0];
    int kcur = c * 256 + lane15;
#pragma unroll
    for (int t = 0; t < 16; ++t) {
      bf16x8 bhi = *(const bf16x8*)(buf + t * 1024 + lane * 8);
      bf16x8 blo = *(const bf16x8*)(buf + t * 1024 + 512 + lane * 8);
      f32x4 acc = __builtin_amdgcn_mfma_f32_16x16x32_bf16(zhi, bhi, zero4, 0, 0, 0);
      acc = __builtin_amdgcn_mfma_f32_16x16x32_bf16(zhi, blo, acc, 0, 0, 0);
      acc = __builtin_amdgcn_mfma_f32_16x16x32_bf16(zlo, bhi, acc, 0, 0, 0);
#pragma unroll
      for (int r = 0; r < 4; ++r) {
        float cv = acc[r];
        bool cond = cv > s1[r];                 // strict: keep earliest on ties
        kb[r] = cond ? kcur : kb[r];
        s2[r] = fmaxf(s2[r], fminf(cv, s1[r])); // running 2nd-best
        s1[r] = fmaxf(s1[r], cv);
      }
      kcur += 16;
    }
  }

  // merge across the 16 lanes sharing this quad's 4 rows
  unsigned long long packed[4];
#pragma unroll
  for (int r = 0; r < 4; ++r) {
    unsigned o = __float_as_uint(s1[r]);
    o = (o & 0x80000000u) ? ~o : (o | 0x80000000u);        // monotone in s1
    packed[r] = ((unsigned long long)o << 32) | (unsigned)(8191 - kb[r]);
  }
#pragma unroll
  for (int m = 1; m <= 8; m <<= 1) {
#pragma unroll
    for (int r = 0; r < 4; ++r) {
      unsigned long long op = __shfl_xor(packed[r], m, 64);
      float os1 = __shfl_xor(s1[r], m, 64);
      float os2 = __shfl_xor(s2[r], m, 64);
      s2[r] = fmaxf(fmaxf(s2[r], os2), fminf(s1[r], os1)); // union 2nd-best
      s1[r] = fmaxf(s1[r], os1);
      packed[r] = (op > packed[r]) ? op : packed[r];        // max s1, tie->min k
    }
  }
  if (lane15 == 0) {
#pragma unroll
    for (int r = 0; r < 4; ++r) {
      int row = g * 16 + quad * 4 + r;
      if (s1[r] - s2[r] < MARGIN) {            // ambiguous -> exact rescore
        int pos = atomicAdd(cnt, 1);
        list[pos] = row;
        idx_ws[row] = -(pos + 1);              // sentinel: resolved via mp2 in epi
      } else {
        idx_ws[row] = 8191 - (int)(unsigned)(packed[r] & 0xFFFFFFFFull);
      }
    }
  }
}

// Exact fp32 rescore, THREAD-PER-CODE: task j = (flag i, k-chunk kc); each of the
// 256 threads scores one code; block-reduce; one atomicMax(mp2[i]) per block.
__global__ __launch_bounds__(256) void k_cleanup(const float* __restrict__ z,
                                                 const float* __restrict__ en,
                                                 const float* __restrict__ en_h,
                                                 const int* __restrict__ list,
                                                 const int* __restrict__ cnt,
                                                 unsigned long long* __restrict__ mp2) {
  __shared__ unsigned long long wred[4];
  const int tid = threadIdx.x;
  const int lane = tid & 63, wid = tid >> 6;
  const int ntask = (*cnt) * 32;               // 32 chunks of 256 codes per row

  for (int j = blockIdx.x; j < ntask; j += gridDim.x) {
    int i = j >> 5, kc = j & 31;
    int row = list[i];
    const float* zr = z + (size_t)row * D;     // wave-uniform -> scalar loads
    float v[D];
    float ss = 0.f;
#pragma unroll
    for (int d = 0; d < D; ++d) v[d] = zr[d];
#pragma unroll
    for (int d = 0; d < D; ++d) ss = fmaf(v[d], v[d], ss);
    float n = fmaxf(sqrtf(ss), EPS);
#pragma unroll
    for (int d = 0; d < D; ++d) v[d] = v[d] / n;

    int k = kc * 256 + tid;                    // contiguous rows -> coalesced
    const float4* er = reinterpret_cast<const float4*>(en + (size_t)k * D);
    float a = -en_h[k];
#pragma unroll
    for (int jj = 0; jj < 8; ++jj) {           // exact R4 fma order
      float4 e = er[jj];
      a = fmaf(v[4 * jj + 0], e.x, a);
      a = fmaf(v[4 * jj + 1], e.y, a);
      a = fmaf(v[4 * jj + 2], e.z, a);
      a = fmaf(v[4 * jj + 3], e.w, a);
    }
    unsigned o = __float_as_uint(a);
    o = (o & 0x80000000u) ? ~o : (o | 0x80000000u);
    unsigned long long pk = ((unsigned long long)o << 32) | (unsigned)(8191 - k);
#pragma unroll
    for (int m = 32; m >= 1; m >>= 1) {
      unsigned long long op = __shfl_xor(pk, m, 64);
      pk = (op > pk) ? op : pk;                // max s, tie -> min k
    }
    if (lane == 0) wred[wid] = pk;
    __syncthreads();
    if (tid == 0) {
      unsigned long long m01 = (wred[0] > wred[1]) ? wred[0] : wred[1];
      unsigned long long m23 = (wred[2] > wred[3]) ? wred[2] : wred[3];
      atomicMax(&mp2[i], (m01 > m23) ? m01 : m23);
    }
    __syncthreads();                           // protect wred for next task
  }
}

__global__ __launch_bounds__(256) void k_epi(const float* __restrict__ z,
                                             const float* __restrict__ en,
                                             const int* __restrict__ idx_ws,
                                             const unsigned long long* __restrict__ mp2,
                                             float* __restrict__ out_z,
                                             float* __restrict__ loss,
                                             float* __restrict__ out_idx,
                                             float scale) {
  int row = blockIdx.x * 256 + threadIdx.x;
  int kb = idx_ws[row];
  if (kb < 0) {                                // flagged: exact result in mp2
    unsigned long long m = mp2[-kb - 1];
    kb = 8191 - (int)(unsigned)(m & 0xFFFFFFFFull);
  }
  out_idx[row] = (float)kb;  // whole out buffer read back as f32

  const float4* p = reinterpret_cast<const float4*>(z + (size_t)row * D);
  float4 q[D / 4];
#pragma unroll
  for (int j = 0; j < D / 4; ++j) q[j] = p[j];
  float ss = 0.f;
#pragma unroll
  for (int j = 0; j < D / 4; ++j)
    ss = fmaf(q[j].x, q[j].x, fmaf(q[j].y, q[j].y, fmaf(q[j].z, q[j].z, fmaf(q[j].w, q[j].w, ss))));
  float n = fmaxf(sqrtf(ss), EPS);

  const float4* ep = reinterpret_cast<const float4*>(en + (size_t)kb * D);
  float4* op = reinterpret_cast<float4*>(out_z + (size_t)row * D);
  float s = 0.f;
#pragma unroll
  for (int j = 0; j < D / 4; ++j) {
    float4 e = ep[j];
    float4 o;
    o.x = q[j].x + (e.x - q[j].x);  // STE forward value, reference op order
    o.y = q[j].y + (e.y - q[j].y);
    o.z = q[j].z + (e.z - q[j].z);
    o.w = q[j].w + (e.w - q[j].w);
    op[j] = o;
    float dx = e.x - q[j].x / n;  float dy = e.y - q[j].y / n;
    float dz = e.z - q[j].z / n;  float dw = e.w - q[j].w / n;
    s = fmaf(dx, dx, fmaf(dy, dy, fmaf(dz, dz, fmaf(dw, dw, s))));
  }

#pragma unroll
  for (int off = 32; off > 0; off >>= 1) s += __shfl_down(s, off, 64);
  __shared__ float wsum[4];
  int lane = threadIdx.x & 63, wid = threadIdx.x >> 6;
  if (lane == 0) wsum[wid] = s;
  __syncthreads();
  if (threadIdx.x == 0) {
    float tt = (wsum[0] + wsum[1]) + (wsum[2] + wsum[3]);
    atomicAdd(loss, tt * scale);
  }
}

extern "C" void kernel_launch(void* const* d_in, const int* in_sizes, int n_in,
                              void* d_out, int out_size, void* d_ws, size_t ws_size,
                              hipStream_t stream) {
  const float* z = (const float*)d_in[0];
  const float* emb = (const float*)d_in[1];
  const int N = in_sizes[0] / D;  // 32768
  const int K = in_sizes[1] / D;  // 8192

  float* out = (float*)d_out;
  float* out_z = out;                        // N*D
  float* loss = out + (size_t)N * D;         // 1
  float* out_idx = out + (size_t)N * D + 1;  // N

  // ws layout (~6.7 MB; R3/R4 WRITE_SIZE proves ws >= 9.4 MB)
  char* w = (char*)d_ws;
  float* en = (float*)w;                         w += (size_t)K * D * 4;     // 1 MB
  float* en_h = (float*)w;                       w += (size_t)K * 4;         // 32 KB
  unsigned short* eswz = (unsigned short*)w;     w += (size_t)K * D * 2 * 2; // 1 MB
  unsigned short* zswz_hi = (unsigned short*)w;  w += (size_t)N * D * 2;     // 2 MB
  unsigned short* zswz_lo = (unsigned short*)w;  w += (size_t)N * D * 2;     // 2 MB
  int* idx_ws = (int*)w;                         w += (size_t)N * 4;         // 128 KB
  int* list = (int*)w;                           w += (size_t)N * 4;         // 128 KB
  unsigned long long* mp2 = (unsigned long long*)w; w += (size_t)N * 8;      // 256 KB
  int* cnt = (int*)w;

  k_prep<<<dim3((K + N) / 256), 256, 0, stream>>>(
      z, emb, en, en_h, eswz, zswz_hi, zswz_lo, cnt, loss, mp2, N);

  k_argmin_mfma<<<dim3(N / 64), 256, 0, stream>>>(
      zswz_hi, zswz_lo, eswz, idx_ws, list, cnt);

  k_cleanup<<<dim3(4096), 256, 0, stream>>>(z, en, en_h, list, cnt, mp2);

  k_epi<<<dim3(N / 256), 256, 0, stream>>>(
      z, en, idx_ws, mp2, out_z, loss, out_idx, 1.25f / (float)((size_t)N * D));
}